// Round 1
// baseline (579.110 us; speedup 1.0000x reference)
//
#include <hip/hip_runtime.h>

#define NN 50000
#define NE 800000
#define IN_C 256
#define HID_C 256
#define OUT_C 128

// ---------------- CSR build ----------------

__global__ __launch_bounds__(256) void hist_kernel(const int* __restrict__ col,
                                                   int* __restrict__ cnt, int E) {
  int e = blockIdx.x * blockDim.x + threadIdx.x;
  if (e < E) atomicAdd(&cnt[col[e]], 1);
}

// single-block exclusive scan over n ints (wave-shuffle based, 3 barriers/chunk)
__global__ __launch_bounds__(1024) void scan_kernel(const int* __restrict__ cnt,
                                                    int* __restrict__ row_off, int n) {
  __shared__ int wsum[16];
  __shared__ int wpre[17];
  __shared__ int carry_s;
  int lane = threadIdx.x & 63;
  int wid = threadIdx.x >> 6;
  if (threadIdx.x == 0) carry_s = 0;
  for (int base = 0; base < n; base += 1024) {
    int i = base + threadIdx.x;
    int v = (i < n) ? cnt[i] : 0;
    int s = v;
#pragma unroll
    for (int off = 1; off < 64; off <<= 1) {
      int t = __shfl_up(s, off, 64);
      if (lane >= off) s += t;
    }
    if (lane == 63) wsum[wid] = s;
    __syncthreads();  // A: wsum ready; carry_s from prev iter visible
    if (threadIdx.x < 16) {
      int ws = wsum[threadIdx.x];
      int ss = ws;
#pragma unroll
      for (int off = 1; off < 16; off <<= 1) {
        int t = __shfl_up(ss, off, 64);
        if (lane >= off) ss += t;
      }
      wpre[threadIdx.x] = ss - ws;
      if (threadIdx.x == 15) wpre[16] = ss;
    }
    __syncthreads();  // B: wpre ready
    int cbase = carry_s;
    int total = wpre[16];
    if (i < n) row_off[i] = cbase + wpre[wid] + (s - v);
    __syncthreads();  // C: all reads of carry_s done
    if (threadIdx.x == 0) carry_s = cbase + total;
  }
  if (threadIdx.x == 0) row_off[n] = carry_s;
}

__global__ __launch_bounds__(256) void init2_kernel(const int* __restrict__ cnt,
                                                    const int* __restrict__ row_off,
                                                    float* __restrict__ dinv,
                                                    int* __restrict__ cursor, int n) {
  int v = blockIdx.x * blockDim.x + threadIdx.x;
  if (v < n) {
    dinv[v] = rsqrtf((float)(cnt[v] + 1));  // +1 self-loop; deg >= 1 always
    cursor[v] = row_off[v];
  }
}

__global__ __launch_bounds__(256) void scatter_kernel(const int* __restrict__ row,
                                                      const int* __restrict__ col,
                                                      const float* __restrict__ dinv,
                                                      int* __restrict__ cursor,
                                                      int* __restrict__ csr_row,
                                                      float* __restrict__ csr_w, int E) {
  int e = blockIdx.x * blockDim.x + threadIdx.x;
  if (e < E) {
    int r = row[e], c = col[e];
    int p = atomicAdd(&cursor[c], 1);
    csr_row[p] = r;
    csr_w[p] = dinv[r] * dinv[c];
  }
}

// ---------------- fp32 tiled GEMM: C[M,N] = A[M,K] * B[K,N] ----------------
// BM=64, BN=64, BK=16, 256 threads, 4x4 micro-tile. N,K multiples of 16/64; M guarded.

__global__ __launch_bounds__(256) void gemm_kernel(const float* __restrict__ A,
                                                   const float* __restrict__ B,
                                                   float* __restrict__ C,
                                                   int M, int N, int K) {
  __shared__ float As[16][68];  // transposed tile, stride 68 (272B, 16B aligned)
  __shared__ float Bs[16][68];
  const int tid = threadIdx.x;
  const int tx = tid & 15;   // N dim
  const int ty = tid >> 4;   // M dim
  const int row0 = blockIdx.y * 64;
  const int col0 = blockIdx.x * 64;

  float acc[4][4] = {};

  const int a_c = tid & 15;   // k within tile
  const int a_r = tid >> 4;   // row base (0..15), +16 steps
  const int b_c = tid & 63;   // col within tile
  const int b_r = tid >> 6;   // k base (0..3), +4 steps

  for (int k0 = 0; k0 < K; k0 += 16) {
#pragma unroll
    for (int i = 0; i < 4; ++i) {
      int r = a_r + i * 16;
      int gr = row0 + r;
      As[a_c][r] = (gr < M) ? A[(size_t)gr * K + k0 + a_c] : 0.0f;
    }
#pragma unroll
    for (int i = 0; i < 4; ++i) {
      int r = b_r + i * 4;
      Bs[r][b_c] = B[(size_t)(k0 + r) * N + col0 + b_c];
    }
    __syncthreads();
#pragma unroll
    for (int kk = 0; kk < 16; ++kk) {
      float4 a = *reinterpret_cast<const float4*>(&As[kk][ty * 4]);
      float4 b = *reinterpret_cast<const float4*>(&Bs[kk][tx * 4]);
      float av[4] = {a.x, a.y, a.z, a.w};
      float bv[4] = {b.x, b.y, b.z, b.w};
#pragma unroll
      for (int i = 0; i < 4; ++i)
#pragma unroll
        for (int j = 0; j < 4; ++j) acc[i][j] += av[i] * bv[j];
    }
    __syncthreads();
  }

#pragma unroll
  for (int i = 0; i < 4; ++i) {
    int gr = row0 + ty * 4 + i;
    if (gr < M) {
      float4 v = make_float4(acc[i][0], acc[i][1], acc[i][2], acc[i][3]);
      *reinterpret_cast<float4*>(&C[(size_t)gr * N + col0 + tx * 4]) = v;
    }
  }
}

// ---------------- aggregation: one wave per node ----------------

__global__ __launch_bounds__(256) void agg256_kernel(const float* __restrict__ h,
                                                     const int* __restrict__ row_off,
                                                     const int* __restrict__ csr_row,
                                                     const float* __restrict__ csr_w,
                                                     const float* __restrict__ dinv,
                                                     const float* __restrict__ bias,
                                                     float* __restrict__ out, int n) {
  int wave = threadIdx.x >> 6;
  int lane = threadIdx.x & 63;
  int v = blockIdx.x * 4 + wave;
  if (v >= n) return;
  int beg = row_off[v], end = row_off[v + 1];
  float4 acc = make_float4(0.f, 0.f, 0.f, 0.f);
  for (int e = beg; e < end; ++e) {
    int r = csr_row[e];
    float w = csr_w[e];
    float4 hv = *reinterpret_cast<const float4*>(&h[(size_t)r * 256 + lane * 4]);
    acc.x += hv.x * w; acc.y += hv.y * w; acc.z += hv.z * w; acc.w += hv.w * w;
  }
  float dv = dinv[v];
  float sw = dv * dv;
  float4 hs = *reinterpret_cast<const float4*>(&h[(size_t)v * 256 + lane * 4]);
  acc.x += hs.x * sw; acc.y += hs.y * sw; acc.z += hs.z * sw; acc.w += hs.w * sw;
  float4 bv = *reinterpret_cast<const float4*>(&bias[lane * 4]);
  acc.x = fmaxf(acc.x + bv.x, 0.f);
  acc.y = fmaxf(acc.y + bv.y, 0.f);
  acc.z = fmaxf(acc.z + bv.z, 0.f);
  acc.w = fmaxf(acc.w + bv.w, 0.f);
  *reinterpret_cast<float4*>(&out[(size_t)v * 256 + lane * 4]) = acc;
}

__global__ __launch_bounds__(256) void agg128_kernel(const float* __restrict__ h,
                                                     const int* __restrict__ row_off,
                                                     const int* __restrict__ csr_row,
                                                     const float* __restrict__ csr_w,
                                                     const float* __restrict__ dinv,
                                                     const float* __restrict__ bias,
                                                     float* __restrict__ out, int n) {
  int wave = threadIdx.x >> 6;
  int lane = threadIdx.x & 63;
  int v = blockIdx.x * 4 + wave;
  if (v >= n) return;
  int beg = row_off[v], end = row_off[v + 1];
  float2 acc = make_float2(0.f, 0.f);
  for (int e = beg; e < end; ++e) {
    int r = csr_row[e];
    float w = csr_w[e];
    float2 hv = *reinterpret_cast<const float2*>(&h[(size_t)r * 128 + lane * 2]);
    acc.x += hv.x * w; acc.y += hv.y * w;
  }
  float dv = dinv[v];
  float sw = dv * dv;
  float2 hs = *reinterpret_cast<const float2*>(&h[(size_t)v * 128 + lane * 2]);
  acc.x += hs.x * sw; acc.y += hs.y * sw;
  float2 bv = *reinterpret_cast<const float2*>(&bias[lane * 2]);
  acc.x += bv.x; acc.y += bv.y;
  *reinterpret_cast<float2*>(&out[(size_t)v * 128 + lane * 2]) = acc;
}

// ---------------- launch ----------------

extern "C" void kernel_launch(void* const* d_in, const int* in_sizes, int n_in,
                              void* d_out, int out_size, void* d_ws, size_t ws_size,
                              hipStream_t stream) {
  const float* x = (const float*)d_in[0];
  const int* ei = (const int*)d_in[1];     // [2, NE] int32
  const float* W1 = (const float*)d_in[2];
  const float* b1 = (const float*)d_in[3];
  const float* W2 = (const float*)d_in[4];
  const float* b2 = (const float*)d_in[5];
  float* out = (float*)d_out;

  const int* row = ei;       // edge_index[0] — message source
  const int* col = ei + NE;  // edge_index[1] — message destination

  // workspace layout
  float* H = (float*)d_ws;                      // [NN,256]  (GEMM1 out; reused for GEMM2 out)
  float* H2 = H + (size_t)NN * 256;             // [NN,256]  (agg1 out / GEMM2 in)
  int* cnt = (int*)(H2 + (size_t)NN * 256);     // [NN]
  int* row_off = cnt + NN;                      // [NN+1]
  int* cursor = row_off + NN + 1;               // [NN]
  float* dinv = (float*)(cursor + NN);          // [NN]
  int* csr_row = (int*)(dinv + NN);             // [NE]
  float* csr_w = (float*)(csr_row + NE);        // [NE]
  float* H3 = H;                                // [NN,128] aliases H (H dead after agg1)

  hipMemsetAsync(cnt, 0, NN * sizeof(int), stream);
  hist_kernel<<<(NE + 255) / 256, 256, 0, stream>>>(col, cnt, NE);
  scan_kernel<<<1, 1024, 0, stream>>>(cnt, row_off, NN);
  init2_kernel<<<(NN + 255) / 256, 256, 0, stream>>>(cnt, row_off, dinv, cursor, NN);
  scatter_kernel<<<(NE + 255) / 256, 256, 0, stream>>>(row, col, dinv, cursor, csr_row, csr_w, NE);

  // layer 1: H = x @ W1 ; H2 = relu(agg(H) + b1)
  {
    dim3 grid(HID_C / 64, (NN + 63) / 64);
    gemm_kernel<<<grid, 256, 0, stream>>>(x, W1, H, NN, HID_C, IN_C);
  }
  agg256_kernel<<<(NN + 3) / 4, 256, 0, stream>>>(H, row_off, csr_row, csr_w, dinv, b1, H2, NN);

  // layer 2: H3 = H2 @ W2 ; out = agg(H3) + b2
  {
    dim3 grid(OUT_C / 64, (NN + 63) / 64);
    gemm_kernel<<<grid, 256, 0, stream>>>(H2, W2, H3, NN, OUT_C, HID_C);
  }
  agg128_kernel<<<(NN + 3) / 4, 256, 0, stream>>>(H3, row_off, csr_row, csr_w, dinv, b2, out, NN);
}

// Round 2
// 443.008 us; speedup vs baseline: 1.3072x; 1.3072x over previous
//
#include <hip/hip_runtime.h>

#define NN 50000
#define NE 800000
#define IN_C 256
#define HID_C 256
#define OUT_C 128

typedef unsigned short u16;
typedef __attribute__((ext_vector_type(8))) short short8;
typedef __attribute__((ext_vector_type(4))) float f32x4;

__device__ __forceinline__ u16 f2b(float f) {
  unsigned int u = __float_as_uint(f);
  return (u16)((u + 0x7FFFu + ((u >> 16) & 1u)) >> 16);  // RNE
}
__device__ __forceinline__ float b2f(u16 s) {
  return __uint_as_float(((unsigned int)s) << 16);
}

// ---------------- CSR build ----------------

__global__ __launch_bounds__(256) void hist_kernel(const int* __restrict__ col,
                                                   int* __restrict__ cnt, int E) {
  int e = blockIdx.x * blockDim.x + threadIdx.x;
  if (e < E) atomicAdd(&cnt[col[e]], 1);
}

__global__ __launch_bounds__(1024) void scan_kernel(const int* __restrict__ cnt,
                                                    int* __restrict__ row_off, int n) {
  __shared__ int wsum[16];
  __shared__ int wpre[17];
  __shared__ int carry_s;
  int lane = threadIdx.x & 63;
  int wid = threadIdx.x >> 6;
  if (threadIdx.x == 0) carry_s = 0;
  for (int base = 0; base < n; base += 1024) {
    int i = base + threadIdx.x;
    int v = (i < n) ? cnt[i] : 0;
    int s = v;
#pragma unroll
    for (int off = 1; off < 64; off <<= 1) {
      int t = __shfl_up(s, off, 64);
      if (lane >= off) s += t;
    }
    if (lane == 63) wsum[wid] = s;
    __syncthreads();
    if (threadIdx.x < 16) {
      int ws = wsum[threadIdx.x];
      int ss = ws;
#pragma unroll
      for (int off = 1; off < 16; off <<= 1) {
        int t = __shfl_up(ss, off, 64);
        if (lane >= off) ss += t;
      }
      wpre[threadIdx.x] = ss - ws;
      if (threadIdx.x == 15) wpre[16] = ss;
    }
    __syncthreads();
    int cbase = carry_s;
    int total = wpre[16];
    if (i < n) row_off[i] = cbase + wpre[wid] + (s - v);
    __syncthreads();
    if (threadIdx.x == 0) carry_s = cbase + total;
  }
  if (threadIdx.x == 0) row_off[n] = carry_s;
}

__global__ __launch_bounds__(256) void init2_kernel(const int* __restrict__ cnt,
                                                    const int* __restrict__ row_off,
                                                    float* __restrict__ dinv,
                                                    int* __restrict__ cursor, int n) {
  int v = blockIdx.x * blockDim.x + threadIdx.x;
  if (v < n) {
    dinv[v] = rsqrtf((float)(cnt[v] + 1));
    cursor[v] = row_off[v];
  }
}

__global__ __launch_bounds__(256) void scatter_kernel(const int* __restrict__ row,
                                                      const int* __restrict__ col,
                                                      const float* __restrict__ dinv,
                                                      int* __restrict__ cursor,
                                                      int* __restrict__ csr_row,
                                                      float* __restrict__ csr_w, int E) {
  int e = blockIdx.x * blockDim.x + threadIdx.x;
  if (e < E) {
    int r = row[e], c = col[e];
    int p = atomicAdd(&cursor[c], 1);
    csr_row[p] = r;
    csr_w[p] = dinv[r] * dinv[c];
  }
}

// ---------------- weight convert+transpose: W[K,N] fp32 -> Wt[N,K] bf16 ----------------

__global__ __launch_bounds__(256) void convw_kernel(const float* __restrict__ W1,
                                                    const float* __restrict__ W2,
                                                    u16* __restrict__ W1t,
                                                    u16* __restrict__ W2t) {
  int id = blockIdx.x * 256 + threadIdx.x;
  if (id < 256 * 256) {
    int n = id >> 8, k = id & 255;
    W1t[id] = f2b(W1[k * 256 + n]);
  }
  if (id < 128 * 256) {
    int n = id >> 8, k = id & 255;
    W2t[id] = f2b(W2[k * 128 + n]);
  }
}

// ---------------- MFMA GEMM: C[M,N]bf16 = A[M,256] * Bt[N,256]^T ----------------
// BM=BN=128, BK=32, 256 threads = 4 waves in 2x2, each wave 4x4 tiles of 16x16x32.

template <bool A_IS_F32>
__global__ __launch_bounds__(256) void gemm_mfma(const void* __restrict__ Ap,
                                                 const u16* __restrict__ Bt,
                                                 u16* __restrict__ C, int M, int N) {
  __shared__ u16 Asl[128 * 40];  // row stride 40 (80B) breaks 8-way bank conflicts
  __shared__ u16 Bsl[128 * 40];
  const int tid = threadIdx.x;
  const int row0 = blockIdx.y * 128;
  const int col0 = blockIdx.x * 128;

  f32x4 acc[4][4] = {};

  const int seg = tid & 7;    // 4-elem k segment
  const int rb = tid >> 3;    // 0..31, +32 steps
  const int wave = tid >> 6, lane = tid & 63;
  const int wm = wave >> 1, wn = wave & 1;
  const int qr = lane & 15, quad = lane >> 4;

  for (int k0 = 0; k0 < 256; k0 += 32) {
    // stage A tile 128x32 -> bf16 LDS
    if (A_IS_F32) {
      const float* A = (const float*)Ap;
#pragma unroll
      for (int i = 0; i < 4; ++i) {
        int r = rb + i * 32;
        int gr = row0 + r;
        float4 v = make_float4(0.f, 0.f, 0.f, 0.f);
        if (gr < M) v = *(const float4*)&A[(size_t)gr * 256 + k0 + seg * 4];
        ushort4 u;
        u.x = f2b(v.x); u.y = f2b(v.y); u.z = f2b(v.z); u.w = f2b(v.w);
        *(ushort4*)&Asl[r * 40 + seg * 4] = u;
      }
    } else {
      const u16* A = (const u16*)Ap;
#pragma unroll
      for (int i = 0; i < 4; ++i) {
        int r = rb + i * 32;
        int gr = row0 + r;
        ushort4 u = make_ushort4(0, 0, 0, 0);
        if (gr < M) u = *(const ushort4*)&A[(size_t)gr * 256 + k0 + seg * 4];
        *(ushort4*)&Asl[r * 40 + seg * 4] = u;
      }
    }
    // stage B tile 128x32 (Bt is n-major bf16, N multiple of 128 -> no guard)
#pragma unroll
    for (int i = 0; i < 4; ++i) {
      int n = rb + i * 32;
      ushort4 u = *(const ushort4*)&Bt[(size_t)(col0 + n) * 256 + k0 + seg * 4];
      *(ushort4*)&Bsl[n * 40 + seg * 4] = u;
    }
    __syncthreads();

    short8 afr[4], bfr[4];
#pragma unroll
    for (int mt = 0; mt < 4; ++mt)
      afr[mt] = *(const short8*)&Asl[(wm * 64 + mt * 16 + qr) * 40 + quad * 8];
#pragma unroll
    for (int nt = 0; nt < 4; ++nt)
      bfr[nt] = *(const short8*)&Bsl[(wn * 64 + nt * 16 + qr) * 40 + quad * 8];
#pragma unroll
    for (int mt = 0; mt < 4; ++mt)
#pragma unroll
      for (int nt = 0; nt < 4; ++nt)
        acc[mt][nt] = __builtin_amdgcn_mfma_f32_16x16x32_bf16(afr[mt], bfr[nt], acc[mt][nt], 0, 0, 0);
    __syncthreads();
  }

  // epilogue: D col=lane&15, row=quad*4+i
#pragma unroll
  for (int mt = 0; mt < 4; ++mt) {
#pragma unroll
    for (int nt = 0; nt < 4; ++nt) {
      int gc = col0 + wn * 64 + nt * 16 + qr;
#pragma unroll
      for (int i = 0; i < 4; ++i) {
        int gr = row0 + wm * 64 + mt * 16 + quad * 4 + i;
        if (gr < M) C[(size_t)gr * N + gc] = f2b(acc[mt][nt][i]);
      }
    }
  }
}

// ---------------- aggregation (bf16 gather, fp32 accumulate) ----------------

__global__ __launch_bounds__(256) void agg256_bf(const u16* __restrict__ h,
                                                 const int* __restrict__ row_off,
                                                 const int* __restrict__ csr_row,
                                                 const float* __restrict__ csr_w,
                                                 const float* __restrict__ dinv,
                                                 const float* __restrict__ bias,
                                                 u16* __restrict__ out, int n) {
  int wave = threadIdx.x >> 6;
  int lane = threadIdx.x & 63;
  int v = blockIdx.x * 4 + wave;
  if (v >= n) return;
  int beg = row_off[v], end = row_off[v + 1];
  float a0 = 0.f, a1 = 0.f, a2 = 0.f, a3 = 0.f;
  for (int e = beg; e < end; ++e) {
    int r = csr_row[e];
    float w = csr_w[e];
    ushort4 hv = *(const ushort4*)&h[(size_t)r * 256 + lane * 4];
    a0 += b2f(hv.x) * w; a1 += b2f(hv.y) * w;
    a2 += b2f(hv.z) * w; a3 += b2f(hv.w) * w;
  }
  float dv = dinv[v];
  float sw = dv * dv;
  ushort4 hs = *(const ushort4*)&h[(size_t)v * 256 + lane * 4];
  a0 += b2f(hs.x) * sw; a1 += b2f(hs.y) * sw;
  a2 += b2f(hs.z) * sw; a3 += b2f(hs.w) * sw;
  float4 bv = *(const float4*)&bias[lane * 4];
  ushort4 o;
  o.x = f2b(fmaxf(a0 + bv.x, 0.f));
  o.y = f2b(fmaxf(a1 + bv.y, 0.f));
  o.z = f2b(fmaxf(a2 + bv.z, 0.f));
  o.w = f2b(fmaxf(a3 + bv.w, 0.f));
  *(ushort4*)&out[(size_t)v * 256 + lane * 4] = o;
}

__global__ __launch_bounds__(256) void agg128_bf(const u16* __restrict__ h,
                                                 const int* __restrict__ row_off,
                                                 const int* __restrict__ csr_row,
                                                 const float* __restrict__ csr_w,
                                                 const float* __restrict__ dinv,
                                                 const float* __restrict__ bias,
                                                 float* __restrict__ out, int n) {
  int wave = threadIdx.x >> 6;
  int lane = threadIdx.x & 63;
  int v = blockIdx.x * 4 + wave;
  if (v >= n) return;
  int beg = row_off[v], end = row_off[v + 1];
  float a0 = 0.f, a1 = 0.f;
  for (int e = beg; e < end; ++e) {
    int r = csr_row[e];
    float w = csr_w[e];
    ushort2 hv = *(const ushort2*)&h[(size_t)r * 128 + lane * 2];
    a0 += b2f(hv.x) * w; a1 += b2f(hv.y) * w;
  }
  float dv = dinv[v];
  float sw = dv * dv;
  ushort2 hs = *(const ushort2*)&h[(size_t)v * 128 + lane * 2];
  a0 += b2f(hs.x) * sw; a1 += b2f(hs.y) * sw;
  float2 bv = *(const float2*)&bias[lane * 2];
  float2 o = make_float2(a0 + bv.x, a1 + bv.y);
  *(float2*)&out[(size_t)v * 128 + lane * 2] = o;
}

// ---------------- launch ----------------

extern "C" void kernel_launch(void* const* d_in, const int* in_sizes, int n_in,
                              void* d_out, int out_size, void* d_ws, size_t ws_size,
                              hipStream_t stream) {
  const float* x = (const float*)d_in[0];
  const int* ei = (const int*)d_in[1];
  const float* W1 = (const float*)d_in[2];
  const float* b1 = (const float*)d_in[3];
  const float* W2 = (const float*)d_in[4];
  const float* b2 = (const float*)d_in[5];
  float* out = (float*)d_out;

  const int* row = ei;
  const int* col = ei + NE;

  // workspace layout (bf16 intermediates)
  u16* Hb = (u16*)d_ws;                       // [NN,256] bf16 GEMM1 out
  u16* H2b = Hb + (size_t)NN * 256;           // [NN,256] bf16 agg1 out / GEMM2 in
  u16* H3b = H2b + (size_t)NN * 256;          // [NN,128] bf16 GEMM2 out
  u16* W1t = H3b + (size_t)NN * 128;          // [256,256] bf16 (transposed)
  u16* W2t = W1t + 256 * 256;                 // [128,256] bf16 (transposed)
  int* cnt = (int*)(W2t + 128 * 256);         // [NN]
  int* row_off = cnt + NN;                    // [NN+1]
  int* cursor = row_off + NN + 1;             // [NN]
  float* dinv = (float*)(cursor + NN);        // [NN]
  int* csr_row = (int*)(dinv + NN);           // [NE]
  float* csr_w = (float*)(csr_row + NE);      // [NE]

  hipMemsetAsync(cnt, 0, NN * sizeof(int), stream);
  convw_kernel<<<256, 256, 0, stream>>>(W1, W2, W1t, W2t);
  hist_kernel<<<(NE + 255) / 256, 256, 0, stream>>>(col, cnt, NE);
  scan_kernel<<<1, 1024, 0, stream>>>(cnt, row_off, NN);
  init2_kernel<<<(NN + 255) / 256, 256, 0, stream>>>(cnt, row_off, dinv, cursor, NN);
  scatter_kernel<<<(NE + 255) / 256, 256, 0, stream>>>(row, col, dinv, cursor, csr_row, csr_w, NE);

  // layer 1: Hb = bf16(x @ W1); H2b = bf16(relu(agg(Hb) + b1))
  {
    dim3 grid(HID_C / 128, (NN + 127) / 128);
    gemm_mfma<true><<<grid, 256, 0, stream>>>(x, W1t, Hb, NN, HID_C);
  }
  agg256_bf<<<(NN + 3) / 4, 256, 0, stream>>>(Hb, row_off, csr_row, csr_w, dinv, b1, H2b, NN);

  // layer 2: H3b = bf16(H2b @ W2); out = agg(H3b) + b2  (fp32 out)
  {
    dim3 grid(OUT_C / 128, (NN + 127) / 128);
    gemm_mfma<false><<<grid, 256, 0, stream>>>(H2b, W2t, H3b, NN, OUT_C);
  }
  agg128_bf<<<(NN + 3) / 4, 256, 0, stream>>>(H3b, row_off, csr_row, csr_w, dinv, b2, out, NN);
}

// Round 3
// 332.919 us; speedup vs baseline: 1.7395x; 1.3307x over previous
//
#include <hip/hip_runtime.h>

#define NN 50000
#define NE 800000
#define IN_C 256
#define HID_C 256
#define OUT_C 128

typedef unsigned short u16;
typedef __attribute__((ext_vector_type(8))) short short8;
typedef __attribute__((ext_vector_type(8))) unsigned short ushort8;
typedef __attribute__((ext_vector_type(4))) float f32x4;

__device__ __forceinline__ u16 f2b(float f) {
  unsigned int u = __float_as_uint(f);
  return (u16)((u + 0x7FFFu + ((u >> 16) & 1u)) >> 16);  // RNE
}
__device__ __forceinline__ float b2f(u16 s) {
  return __uint_as_float(((unsigned int)s) << 16);
}

// ---------------- CSR build ----------------

__global__ __launch_bounds__(256) void hist_kernel(const int* __restrict__ col,
                                                   int* __restrict__ cnt, int E) {
  int e = blockIdx.x * blockDim.x + threadIdx.x;
  if (e < E) atomicAdd(&cnt[col[e]], 1);
}

// per-block sums of 256-element chunks
__global__ __launch_bounds__(256) void scan1_kernel(const int* __restrict__ cnt,
                                                    int* __restrict__ bsum, int n) {
  __shared__ int ws[4];
  int i = blockIdx.x * 256 + threadIdx.x;
  int lane = threadIdx.x & 63, wid = threadIdx.x >> 6;
  int v = (i < n) ? cnt[i] : 0;
#pragma unroll
  for (int off = 32; off > 0; off >>= 1) v += __shfl_down(v, off, 64);
  if (lane == 0) ws[wid] = v;
  __syncthreads();
  if (threadIdx.x == 0) bsum[blockIdx.x] = ws[0] + ws[1] + ws[2] + ws[3];
}

// single block: exclusive scan of nb block sums -> boff; total -> row_off[n]
__global__ __launch_bounds__(256) void scan2_kernel(const int* __restrict__ bsum,
                                                    int* __restrict__ boff,
                                                    int* __restrict__ row_off,
                                                    int nb, int n) {
  __shared__ int wsum[4], wpre[5];
  int lane = threadIdx.x & 63, wid = threadIdx.x >> 6;
  int v = (threadIdx.x < nb) ? bsum[threadIdx.x] : 0;
  int s = v;
#pragma unroll
  for (int off = 1; off < 64; off <<= 1) {
    int t = __shfl_up(s, off, 64);
    if (lane >= off) s += t;
  }
  if (lane == 63) wsum[wid] = s;
  __syncthreads();
  if (threadIdx.x == 0) {
    int acc = 0;
#pragma unroll
    for (int w = 0; w < 4; ++w) { wpre[w] = acc; acc += wsum[w]; }
    wpre[4] = acc;
  }
  __syncthreads();
  if (threadIdx.x < nb) boff[threadIdx.x] = wpre[wid] + (s - v);
  if (threadIdx.x == 0) row_off[n] = wpre[4];
}

// finalize: row_off / cursor / dinv (fused init2)
__global__ __launch_bounds__(256) void scan3_kernel(const int* __restrict__ cnt,
                                                    const int* __restrict__ boff,
                                                    int* __restrict__ row_off,
                                                    int* __restrict__ cursor,
                                                    float* __restrict__ dinv, int n) {
  __shared__ int wsum[4], wpre[4];
  int i = blockIdx.x * 256 + threadIdx.x;
  int lane = threadIdx.x & 63, wid = threadIdx.x >> 6;
  int v = (i < n) ? cnt[i] : 0;
  int s = v;
#pragma unroll
  for (int off = 1; off < 64; off <<= 1) {
    int t = __shfl_up(s, off, 64);
    if (lane >= off) s += t;
  }
  if (lane == 63) wsum[wid] = s;
  __syncthreads();
  if (threadIdx.x == 0) {
    int acc = 0;
#pragma unroll
    for (int w = 0; w < 4; ++w) { wpre[w] = acc; acc += wsum[w]; }
  }
  __syncthreads();
  if (i < n) {
    int off = boff[blockIdx.x] + wpre[wid] + (s - v);
    row_off[i] = off;
    cursor[i] = off;
    dinv[i] = rsqrtf((float)(v + 1));
  }
}

__global__ __launch_bounds__(256) void scatter_kernel(const int* __restrict__ row,
                                                      const int* __restrict__ col,
                                                      const float* __restrict__ dinv,
                                                      int* __restrict__ cursor,
                                                      int2* __restrict__ csr, int E) {
  int e = blockIdx.x * blockDim.x + threadIdx.x;
  if (e < E) {
    int r = row[e], c = col[e];
    int p = atomicAdd(&cursor[c], 1);
    csr[p] = make_int2(r, __float_as_int(dinv[r] * dinv[c]));
  }
}

// ---------------- weight convert+transpose ----------------

__global__ __launch_bounds__(256) void convw_kernel(const float* __restrict__ W1,
                                                    const float* __restrict__ W2,
                                                    u16* __restrict__ W1t,
                                                    u16* __restrict__ W2t) {
  int id = blockIdx.x * 256 + threadIdx.x;
  if (id < 256 * 256) {
    int n = id >> 8, k = id & 255;
    W1t[id] = f2b(W1[k * 256 + n]);
  }
  if (id < 128 * 256) {
    int n = id >> 8, k = id & 255;
    W2t[id] = f2b(W2[k * 128 + n]);
  }
}

// ---------------- MFMA GEMM: C[M,N]bf16 = A[M,256] * Bt[N,256]^T ----------------

template <bool A_IS_F32>
__global__ __launch_bounds__(256) void gemm_mfma(const void* __restrict__ Ap,
                                                 const u16* __restrict__ Bt,
                                                 u16* __restrict__ C, int M, int N) {
  __shared__ u16 Asl[128 * 40];
  __shared__ u16 Bsl[128 * 40];
  const int tid = threadIdx.x;
  const int row0 = blockIdx.y * 128;
  const int col0 = blockIdx.x * 128;

  f32x4 acc[4][4] = {};

  const int seg = tid & 7;
  const int rb = tid >> 3;
  const int wave = tid >> 6, lane = tid & 63;
  const int wm = wave >> 1, wn = wave & 1;
  const int qr = lane & 15, quad = lane >> 4;

  for (int k0 = 0; k0 < 256; k0 += 32) {
    if (A_IS_F32) {
      const float* A = (const float*)Ap;
#pragma unroll
      for (int i = 0; i < 4; ++i) {
        int r = rb + i * 32;
        int gr = row0 + r;
        float4 v = make_float4(0.f, 0.f, 0.f, 0.f);
        if (gr < M) v = *(const float4*)&A[(size_t)gr * 256 + k0 + seg * 4];
        ushort4 u;
        u.x = f2b(v.x); u.y = f2b(v.y); u.z = f2b(v.z); u.w = f2b(v.w);
        *(ushort4*)&Asl[r * 40 + seg * 4] = u;
      }
    } else {
      const u16* A = (const u16*)Ap;
#pragma unroll
      for (int i = 0; i < 4; ++i) {
        int r = rb + i * 32;
        int gr = row0 + r;
        ushort4 u = make_ushort4(0, 0, 0, 0);
        if (gr < M) u = *(const ushort4*)&A[(size_t)gr * 256 + k0 + seg * 4];
        *(ushort4*)&Asl[r * 40 + seg * 4] = u;
      }
    }
#pragma unroll
    for (int i = 0; i < 4; ++i) {
      int n = rb + i * 32;
      ushort4 u = *(const ushort4*)&Bt[(size_t)(col0 + n) * 256 + k0 + seg * 4];
      *(ushort4*)&Bsl[n * 40 + seg * 4] = u;
    }
    __syncthreads();

    short8 afr[4], bfr[4];
#pragma unroll
    for (int mt = 0; mt < 4; ++mt)
      afr[mt] = *(const short8*)&Asl[(wm * 64 + mt * 16 + qr) * 40 + quad * 8];
#pragma unroll
    for (int nt = 0; nt < 4; ++nt)
      bfr[nt] = *(const short8*)&Bsl[(wn * 64 + nt * 16 + qr) * 40 + quad * 8];
#pragma unroll
    for (int mt = 0; mt < 4; ++mt)
#pragma unroll
      for (int nt = 0; nt < 4; ++nt)
        acc[mt][nt] = __builtin_amdgcn_mfma_f32_16x16x32_bf16(afr[mt], bfr[nt], acc[mt][nt], 0, 0, 0);
    __syncthreads();
  }

#pragma unroll
  for (int mt = 0; mt < 4; ++mt) {
#pragma unroll
    for (int nt = 0; nt < 4; ++nt) {
      int gc = col0 + wn * 64 + nt * 16 + qr;
#pragma unroll
      for (int i = 0; i < 4; ++i) {
        int gr = row0 + wm * 64 + mt * 16 + quad * 4 + i;
        if (gr < M) C[(size_t)gr * N + gc] = f2b(acc[mt][nt][i]);
      }
    }
  }
}

// ---------------- aggregation v2: multi-node waves, 16B gathers, 2x unroll ----------------

// 256 ch: 2 nodes/wave, 32 lanes x 8 ch each
__global__ __launch_bounds__(256) void agg256_bf(const u16* __restrict__ h,
                                                 const int* __restrict__ row_off,
                                                 const int2* __restrict__ csr,
                                                 const float* __restrict__ dinv,
                                                 const float* __restrict__ bias,
                                                 u16* __restrict__ out, int n) {
  int wave = threadIdx.x >> 6;
  int lane = threadIdx.x & 63;
  int half = lane >> 5;
  int sl = lane & 31;
  int v = blockIdx.x * 8 + wave * 2 + half;
  if (v >= n) return;
  int beg = row_off[v], end = row_off[v + 1];
  float a[8] = {};
  int e = beg;
  for (; e + 1 < end; e += 2) {
    int2 e0 = csr[e], e1 = csr[e + 1];
    ushort8 h0 = *(const ushort8*)&h[(size_t)e0.x * 256 + sl * 8];
    ushort8 h1 = *(const ushort8*)&h[(size_t)e1.x * 256 + sl * 8];
    float w0 = __int_as_float(e0.y), w1 = __int_as_float(e1.y);
#pragma unroll
    for (int i = 0; i < 8; ++i)
      a[i] += b2f((u16)h0[i]) * w0 + b2f((u16)h1[i]) * w1;
  }
  if (e < end) {
    int2 e0 = csr[e];
    ushort8 h0 = *(const ushort8*)&h[(size_t)e0.x * 256 + sl * 8];
    float w0 = __int_as_float(e0.y);
#pragma unroll
    for (int i = 0; i < 8; ++i) a[i] += b2f((u16)h0[i]) * w0;
  }
  float dv = dinv[v];
  float sw = dv * dv;
  ushort8 hs = *(const ushort8*)&h[(size_t)v * 256 + sl * 8];
  float4 bv0 = *(const float4*)&bias[sl * 8];
  float4 bv1 = *(const float4*)&bias[sl * 8 + 4];
  float bb[8] = {bv0.x, bv0.y, bv0.z, bv0.w, bv1.x, bv1.y, bv1.z, bv1.w};
  ushort8 o;
#pragma unroll
  for (int i = 0; i < 8; ++i) {
    float r = fmaxf(a[i] + b2f((u16)hs[i]) * sw + bb[i], 0.f);
    o[i] = (short)f2b(r);
  }
  *(ushort8*)&out[(size_t)v * 256 + sl * 8] = o;
}

// 128 ch: 4 nodes/wave, 16 lanes x 8 ch each; fp32 output
__global__ __launch_bounds__(256) void agg128_bf(const u16* __restrict__ h,
                                                 const int* __restrict__ row_off,
                                                 const int2* __restrict__ csr,
                                                 const float* __restrict__ dinv,
                                                 const float* __restrict__ bias,
                                                 float* __restrict__ out, int n) {
  int wave = threadIdx.x >> 6;
  int lane = threadIdx.x & 63;
  int quarter = lane >> 4;
  int sl = lane & 15;
  int v = blockIdx.x * 16 + wave * 4 + quarter;
  if (v >= n) return;
  int beg = row_off[v], end = row_off[v + 1];
  float a[8] = {};
  int e = beg;
  for (; e + 1 < end; e += 2) {
    int2 e0 = csr[e], e1 = csr[e + 1];
    ushort8 h0 = *(const ushort8*)&h[(size_t)e0.x * 128 + sl * 8];
    ushort8 h1 = *(const ushort8*)&h[(size_t)e1.x * 128 + sl * 8];
    float w0 = __int_as_float(e0.y), w1 = __int_as_float(e1.y);
#pragma unroll
    for (int i = 0; i < 8; ++i)
      a[i] += b2f((u16)h0[i]) * w0 + b2f((u16)h1[i]) * w1;
  }
  if (e < end) {
    int2 e0 = csr[e];
    ushort8 h0 = *(const ushort8*)&h[(size_t)e0.x * 128 + sl * 8];
    float w0 = __int_as_float(e0.y);
#pragma unroll
    for (int i = 0; i < 8; ++i) a[i] += b2f((u16)h0[i]) * w0;
  }
  float dv = dinv[v];
  float sw = dv * dv;
  ushort8 hs = *(const ushort8*)&h[(size_t)v * 128 + sl * 8];
  float4 bv0 = *(const float4*)&bias[sl * 8];
  float4 bv1 = *(const float4*)&bias[sl * 8 + 4];
  float bb[8] = {bv0.x, bv0.y, bv0.z, bv0.w, bv1.x, bv1.y, bv1.z, bv1.w};
  float o[8];
#pragma unroll
  for (int i = 0; i < 8; ++i) o[i] = a[i] + b2f((u16)hs[i]) * sw + bb[i];
  *(float4*)&out[(size_t)v * 128 + sl * 8] = make_float4(o[0], o[1], o[2], o[3]);
  *(float4*)&out[(size_t)v * 128 + sl * 8 + 4] = make_float4(o[4], o[5], o[6], o[7]);
}

// ---------------- launch ----------------

extern "C" void kernel_launch(void* const* d_in, const int* in_sizes, int n_in,
                              void* d_out, int out_size, void* d_ws, size_t ws_size,
                              hipStream_t stream) {
  const float* x = (const float*)d_in[0];
  const int* ei = (const int*)d_in[1];
  const float* W1 = (const float*)d_in[2];
  const float* b1 = (const float*)d_in[3];
  const float* W2 = (const float*)d_in[4];
  const float* b2 = (const float*)d_in[5];
  float* out = (float*)d_out;

  const int* row = ei;
  const int* col = ei + NE;

  const int NB = (NN + 255) / 256;  // 196 scan blocks

  u16* Hb = (u16*)d_ws;                       // [NN,256] bf16
  u16* H2b = Hb + (size_t)NN * 256;           // [NN,256] bf16
  u16* H3b = H2b + (size_t)NN * 256;          // [NN,128] bf16
  u16* W1t = H3b + (size_t)NN * 128;          // [256,256] bf16
  u16* W2t = W1t + 256 * 256;                 // [128,256] bf16
  int* cnt = (int*)(W2t + 128 * 256);         // [NN]
  int* row_off = cnt + NN;                    // [NN+1]
  int* cursor = row_off + NN + 1;             // [NN]
  float* dinv = (float*)(cursor + NN);        // [NN]
  int* bsum = (int*)(dinv + NN);              // [NB]
  int* boff = bsum + NB;                      // [NB]
  int2* csr = (int2*)(boff + NB);             // [NE] {src, w_bits}

  hipMemsetAsync(cnt, 0, NN * sizeof(int), stream);
  convw_kernel<<<256, 256, 0, stream>>>(W1, W2, W1t, W2t);
  hist_kernel<<<(NE + 255) / 256, 256, 0, stream>>>(col, cnt, NE);
  scan1_kernel<<<NB, 256, 0, stream>>>(cnt, bsum, NN);
  scan2_kernel<<<1, 256, 0, stream>>>(bsum, boff, row_off, NB, NN);
  scan3_kernel<<<NB, 256, 0, stream>>>(cnt, boff, row_off, cursor, dinv, NN);
  scatter_kernel<<<(NE + 255) / 256, 256, 0, stream>>>(row, col, dinv, cursor, csr, NE);

  {
    dim3 grid(HID_C / 128, (NN + 127) / 128);
    gemm_mfma<true><<<grid, 256, 0, stream>>>(x, W1t, Hb, NN, HID_C);
  }
  agg256_bf<<<(NN + 7) / 8, 256, 0, stream>>>(Hb, row_off, csr, dinv, b1, H2b, NN);

  {
    dim3 grid(OUT_C / 128, (NN + 127) / 128);
    gemm_mfma<false><<<grid, 256, 0, stream>>>(H2b, W2t, H3b, NN, OUT_C);
  }
  agg128_bf<<<(NN + 15) / 16, 256, 0, stream>>>(H3b, row_off, csr, dinv, b2, out, NN);
}

// Round 4
// 307.666 us; speedup vs baseline: 1.8823x; 1.0821x over previous
//
#include <hip/hip_runtime.h>

#define NN 50000
#define NE 800000
#define IN_C 256
#define HID_C 256
#define OUT_C 128

typedef unsigned short u16;
typedef __attribute__((ext_vector_type(8))) short short8;
typedef __attribute__((ext_vector_type(8))) unsigned short ushort8;
typedef __attribute__((ext_vector_type(4))) float f32x4;

__device__ __forceinline__ u16 f2b(float f) {
  unsigned int u = __float_as_uint(f);
  return (u16)((u + 0x7FFFu + ((u >> 16) & 1u)) >> 16);  // RNE
}
__device__ __forceinline__ float b2f(u16 s) {
  return __uint_as_float(((unsigned int)s) << 16);
}

// ---------------- CSR build ----------------

__global__ __launch_bounds__(256) void hist_kernel(const int* __restrict__ col,
                                                   int* __restrict__ cnt, int E) {
  int e = blockIdx.x * blockDim.x + threadIdx.x;
  if (e < E) atomicAdd(&cnt[col[e]], 1);
}

__global__ __launch_bounds__(256) void scan1_kernel(const int* __restrict__ cnt,
                                                    int* __restrict__ bsum, int n) {
  __shared__ int ws[4];
  int i = blockIdx.x * 256 + threadIdx.x;
  int lane = threadIdx.x & 63, wid = threadIdx.x >> 6;
  int v = (i < n) ? cnt[i] : 0;
#pragma unroll
  for (int off = 32; off > 0; off >>= 1) v += __shfl_down(v, off, 64);
  if (lane == 0) ws[wid] = v;
  __syncthreads();
  if (threadIdx.x == 0) bsum[blockIdx.x] = ws[0] + ws[1] + ws[2] + ws[3];
}

__global__ __launch_bounds__(256) void scan2_kernel(const int* __restrict__ bsum,
                                                    int* __restrict__ boff,
                                                    int* __restrict__ row_off,
                                                    int nb, int n) {
  __shared__ int wsum[4], wpre[5];
  int lane = threadIdx.x & 63, wid = threadIdx.x >> 6;
  int v = (threadIdx.x < nb) ? bsum[threadIdx.x] : 0;
  int s = v;
#pragma unroll
  for (int off = 1; off < 64; off <<= 1) {
    int t = __shfl_up(s, off, 64);
    if (lane >= off) s += t;
  }
  if (lane == 63) wsum[wid] = s;
  __syncthreads();
  if (threadIdx.x == 0) {
    int acc = 0;
#pragma unroll
    for (int w = 0; w < 4; ++w) { wpre[w] = acc; acc += wsum[w]; }
    wpre[4] = acc;
  }
  __syncthreads();
  if (threadIdx.x < nb) boff[threadIdx.x] = wpre[wid] + (s - v);
  if (threadIdx.x == 0) row_off[n] = wpre[4];
}

__global__ __launch_bounds__(256) void scan3_kernel(const int* __restrict__ cnt,
                                                    const int* __restrict__ boff,
                                                    int* __restrict__ row_off,
                                                    int* __restrict__ cursor,
                                                    float* __restrict__ dinv, int n) {
  __shared__ int wsum[4], wpre[4];
  int i = blockIdx.x * 256 + threadIdx.x;
  int lane = threadIdx.x & 63, wid = threadIdx.x >> 6;
  int v = (i < n) ? cnt[i] : 0;
  int s = v;
#pragma unroll
  for (int off = 1; off < 64; off <<= 1) {
    int t = __shfl_up(s, off, 64);
    if (lane >= off) s += t;
  }
  if (lane == 63) wsum[wid] = s;
  __syncthreads();
  if (threadIdx.x == 0) {
    int acc = 0;
#pragma unroll
    for (int w = 0; w < 4; ++w) { wpre[w] = acc; acc += wsum[w]; }
  }
  __syncthreads();
  if (i < n) {
    int off = boff[blockIdx.x] + wpre[wid] + (s - v);
    row_off[i] = off;
    cursor[i] = off;
    dinv[i] = rsqrtf((float)(v + 1));
  }
}

__global__ __launch_bounds__(256) void scatter_kernel(const int* __restrict__ row,
                                                      const int* __restrict__ col,
                                                      const float* __restrict__ dinv,
                                                      int* __restrict__ cursor,
                                                      int2* __restrict__ csr, int E) {
  int e = blockIdx.x * blockDim.x + threadIdx.x;
  if (e < E) {
    int r = row[e], c = col[e];
    int p = atomicAdd(&cursor[c], 1);
    csr[p] = make_int2(r, __float_as_int(dinv[r] * dinv[c]));
  }
}

// ---------------- weight convert+transpose ----------------

__global__ __launch_bounds__(256) void convw_kernel(const float* __restrict__ W1,
                                                    const float* __restrict__ W2,
                                                    u16* __restrict__ W1t,
                                                    u16* __restrict__ W2t) {
  int id = blockIdx.x * 256 + threadIdx.x;
  if (id < 256 * 256) {
    int n = id >> 8, k = id & 255;
    W1t[id] = f2b(W1[k * 256 + n]);
  }
  if (id < 128 * 256) {
    int n = id >> 8, k = id & 255;
    W2t[id] = f2b(W2[k * 128 + n]);
  }
}

// ---------------- MFMA GEMM, software-pipelined ----------------
// C[M,N]bf16 = A[M,256] * Bt[N,256]^T.  BM=BN=128, BK=32, 256 thr = 4 waves 2x2.
// Register prefetch of tile k+1 overlaps MFMA on tile k; double-buffered LDS;
// ONE barrier per K-iter.

template <bool A_IS_F32>
__global__ __launch_bounds__(256) void gemm_mfma(const void* __restrict__ Ap,
                                                 const u16* __restrict__ Bt,
                                                 u16* __restrict__ C, int M, int N) {
  __shared__ u16 Asl[2][128 * 40];
  __shared__ u16 Bsl[2][128 * 40];
  const int tid = threadIdx.x;
  const int row0 = blockIdx.y * 128;
  const int col0 = blockIdx.x * 128;

  f32x4 acc[4][4] = {};

  const int seg = tid & 7;
  const int rb = tid >> 3;
  const int wave = tid >> 6, lane = tid & 63;
  const int wm = wave >> 1, wn = wave & 1;
  const int qr = lane & 15, quad = lane >> 4;

  float4 aF[4];
  ushort4 aU[4];
  ushort4 bR[4];

  auto load_tiles = [&](int k0) {
    if constexpr (A_IS_F32) {
      const float* A = (const float*)Ap;
#pragma unroll
      for (int i = 0; i < 4; ++i) {
        int gr = row0 + rb + i * 32;
        aF[i] = (gr < M) ? *(const float4*)&A[(size_t)gr * 256 + k0 + seg * 4]
                         : make_float4(0.f, 0.f, 0.f, 0.f);
      }
    } else {
      const u16* A = (const u16*)Ap;
#pragma unroll
      for (int i = 0; i < 4; ++i) {
        int gr = row0 + rb + i * 32;
        aU[i] = (gr < M) ? *(const ushort4*)&A[(size_t)gr * 256 + k0 + seg * 4]
                         : make_ushort4(0, 0, 0, 0);
      }
    }
#pragma unroll
    for (int i = 0; i < 4; ++i) {
      int n = rb + i * 32;
      bR[i] = *(const ushort4*)&Bt[(size_t)(col0 + n) * 256 + k0 + seg * 4];
    }
  };

  auto write_lds = [&](int buf) {
#pragma unroll
    for (int i = 0; i < 4; ++i) {
      int r = rb + i * 32;
      ushort4 u;
      if constexpr (A_IS_F32) {
        u.x = f2b(aF[i].x); u.y = f2b(aF[i].y);
        u.z = f2b(aF[i].z); u.w = f2b(aF[i].w);
      } else {
        u = aU[i];
      }
      *(ushort4*)&Asl[buf][r * 40 + seg * 4] = u;
      *(ushort4*)&Bsl[buf][r * 40 + seg * 4] = bR[i];
    }
  };

  load_tiles(0);
  write_lds(0);
  __syncthreads();

#pragma unroll
  for (int it = 0; it < 8; ++it) {
    const int cur = it & 1;
    if (it < 7) load_tiles((it + 1) * 32);  // prefetch overlaps MFMA below

    short8 afr[4], bfr[4];
#pragma unroll
    for (int mt = 0; mt < 4; ++mt)
      afr[mt] = *(const short8*)&Asl[cur][(wm * 64 + mt * 16 + qr) * 40 + quad * 8];
#pragma unroll
    for (int nt = 0; nt < 4; ++nt)
      bfr[nt] = *(const short8*)&Bsl[cur][(wn * 64 + nt * 16 + qr) * 40 + quad * 8];
#pragma unroll
    for (int mt = 0; mt < 4; ++mt)
#pragma unroll
      for (int nt = 0; nt < 4; ++nt)
        acc[mt][nt] = __builtin_amdgcn_mfma_f32_16x16x32_bf16(afr[mt], bfr[nt], acc[mt][nt], 0, 0, 0);

    if (it < 7) {
      write_lds(1 - cur);  // waits vmcnt; other buffer, no hazard with readers
      __syncthreads();
    }
  }

#pragma unroll
  for (int mt = 0; mt < 4; ++mt) {
#pragma unroll
    for (int nt = 0; nt < 4; ++nt) {
      int gc = col0 + wn * 64 + nt * 16 + qr;
#pragma unroll
      for (int i = 0; i < 4; ++i) {
        int gr = row0 + wm * 64 + mt * 16 + quad * 4 + i;
        if (gr < M) C[(size_t)gr * N + gc] = f2b(acc[mt][nt][i]);
      }
    }
  }
}

// ---------------- aggregation: multi-node waves, 16B gathers, 4x unroll ----------------

__global__ __launch_bounds__(256) void agg256_bf(const u16* __restrict__ h,
                                                 const int* __restrict__ row_off,
                                                 const int2* __restrict__ csr,
                                                 const float* __restrict__ dinv,
                                                 const float* __restrict__ bias,
                                                 u16* __restrict__ out, int n) {
  int wave = threadIdx.x >> 6;
  int lane = threadIdx.x & 63;
  int half = lane >> 5;
  int sl = lane & 31;
  int v = blockIdx.x * 8 + wave * 2 + half;
  if (v >= n) return;
  int beg = row_off[v], end = row_off[v + 1];
  float a[8] = {};
  int e = beg;
  for (; e + 3 < end; e += 4) {
    int2 e0 = csr[e], e1 = csr[e + 1], e2 = csr[e + 2], e3 = csr[e + 3];
    ushort8 h0 = *(const ushort8*)&h[(size_t)e0.x * 256 + sl * 8];
    ushort8 h1 = *(const ushort8*)&h[(size_t)e1.x * 256 + sl * 8];
    ushort8 h2 = *(const ushort8*)&h[(size_t)e2.x * 256 + sl * 8];
    ushort8 h3 = *(const ushort8*)&h[(size_t)e3.x * 256 + sl * 8];
    float w0 = __int_as_float(e0.y), w1 = __int_as_float(e1.y);
    float w2 = __int_as_float(e2.y), w3 = __int_as_float(e3.y);
#pragma unroll
    for (int i = 0; i < 8; ++i)
      a[i] += b2f((u16)h0[i]) * w0 + b2f((u16)h1[i]) * w1 +
              b2f((u16)h2[i]) * w2 + b2f((u16)h3[i]) * w3;
  }
  for (; e < end; ++e) {
    int2 e0 = csr[e];
    ushort8 h0 = *(const ushort8*)&h[(size_t)e0.x * 256 + sl * 8];
    float w0 = __int_as_float(e0.y);
#pragma unroll
    for (int i = 0; i < 8; ++i) a[i] += b2f((u16)h0[i]) * w0;
  }
  float dv = dinv[v];
  float sw = dv * dv;
  ushort8 hs = *(const ushort8*)&h[(size_t)v * 256 + sl * 8];
  float4 bv0 = *(const float4*)&bias[sl * 8];
  float4 bv1 = *(const float4*)&bias[sl * 8 + 4];
  float bb[8] = {bv0.x, bv0.y, bv0.z, bv0.w, bv1.x, bv1.y, bv1.z, bv1.w};
  ushort8 o;
#pragma unroll
  for (int i = 0; i < 8; ++i) {
    float r = fmaxf(a[i] + b2f((u16)hs[i]) * sw + bb[i], 0.f);
    o[i] = (short)f2b(r);
  }
  *(ushort8*)&out[(size_t)v * 256 + sl * 8] = o;
}

__global__ __launch_bounds__(256) void agg128_bf(const u16* __restrict__ h,
                                                 const int* __restrict__ row_off,
                                                 const int2* __restrict__ csr,
                                                 const float* __restrict__ dinv,
                                                 const float* __restrict__ bias,
                                                 float* __restrict__ out, int n) {
  int wave = threadIdx.x >> 6;
  int lane = threadIdx.x & 63;
  int quarter = lane >> 4;
  int sl = lane & 15;
  int v = blockIdx.x * 16 + wave * 4 + quarter;
  if (v >= n) return;
  int beg = row_off[v], end = row_off[v + 1];
  float a[8] = {};
  int e = beg;
  for (; e + 3 < end; e += 4) {
    int2 e0 = csr[e], e1 = csr[e + 1], e2 = csr[e + 2], e3 = csr[e + 3];
    ushort8 h0 = *(const ushort8*)&h[(size_t)e0.x * 128 + sl * 8];
    ushort8 h1 = *(const ushort8*)&h[(size_t)e1.x * 128 + sl * 8];
    ushort8 h2 = *(const ushort8*)&h[(size_t)e2.x * 128 + sl * 8];
    ushort8 h3 = *(const ushort8*)&h[(size_t)e3.x * 128 + sl * 8];
    float w0 = __int_as_float(e0.y), w1 = __int_as_float(e1.y);
    float w2 = __int_as_float(e2.y), w3 = __int_as_float(e3.y);
#pragma unroll
    for (int i = 0; i < 8; ++i)
      a[i] += b2f((u16)h0[i]) * w0 + b2f((u16)h1[i]) * w1 +
              b2f((u16)h2[i]) * w2 + b2f((u16)h3[i]) * w3;
  }
  for (; e < end; ++e) {
    int2 e0 = csr[e];
    ushort8 h0 = *(const ushort8*)&h[(size_t)e0.x * 128 + sl * 8];
    float w0 = __int_as_float(e0.y);
#pragma unroll
    for (int i = 0; i < 8; ++i) a[i] += b2f((u16)h0[i]) * w0;
  }
  float dv = dinv[v];
  float sw = dv * dv;
  ushort8 hs = *(const ushort8*)&h[(size_t)v * 128 + sl * 8];
  float4 bv0 = *(const float4*)&bias[sl * 8];
  float4 bv1 = *(const float4*)&bias[sl * 8 + 4];
  float bb[8] = {bv0.x, bv0.y, bv0.z, bv0.w, bv1.x, bv1.y, bv1.z, bv1.w};
  float o[8];
#pragma unroll
  for (int i = 0; i < 8; ++i) o[i] = a[i] + b2f((u16)hs[i]) * sw + bb[i];
  *(float4*)&out[(size_t)v * 128 + sl * 8] = make_float4(o[0], o[1], o[2], o[3]);
  *(float4*)&out[(size_t)v * 128 + sl * 8 + 4] = make_float4(o[4], o[5], o[6], o[7]);
}

// ---------------- launch ----------------

extern "C" void kernel_launch(void* const* d_in, const int* in_sizes, int n_in,
                              void* d_out, int out_size, void* d_ws, size_t ws_size,
                              hipStream_t stream) {
  const float* x = (const float*)d_in[0];
  const int* ei = (const int*)d_in[1];
  const float* W1 = (const float*)d_in[2];
  const float* b1 = (const float*)d_in[3];
  const float* W2 = (const float*)d_in[4];
  const float* b2 = (const float*)d_in[5];
  float* out = (float*)d_out;

  const int* row = ei;
  const int* col = ei + NE;

  const int NB = (NN + 255) / 256;

  u16* Hb = (u16*)d_ws;                       // [NN,256] bf16
  u16* H2b = Hb + (size_t)NN * 256;           // [NN,256] bf16
  u16* H3b = H2b + (size_t)NN * 256;          // [NN,128] bf16
  u16* W1t = H3b + (size_t)NN * 128;          // [256,256] bf16
  u16* W2t = W1t + 256 * 256;                 // [128,256] bf16
  int* cnt = (int*)(W2t + 128 * 256);         // [NN]
  int* row_off = cnt + NN;                    // [NN+1]
  int* cursor = row_off + NN + 1;             // [NN]
  float* dinv = (float*)(cursor + NN);        // [NN]
  int* bsum = (int*)(dinv + NN);              // [NB]
  int* boff = bsum + NB;                      // [NB]
  int2* csr = (int2*)(boff + NB);             // [NE] {src, w_bits}

  hipMemsetAsync(cnt, 0, NN * sizeof(int), stream);
  convw_kernel<<<256, 256, 0, stream>>>(W1, W2, W1t, W2t);
  hist_kernel<<<(NE + 255) / 256, 256, 0, stream>>>(col, cnt, NE);
  scan1_kernel<<<NB, 256, 0, stream>>>(cnt, bsum, NN);
  scan2_kernel<<<1, 256, 0, stream>>>(bsum, boff, row_off, NB, NN);
  scan3_kernel<<<NB, 256, 0, stream>>>(cnt, boff, row_off, cursor, dinv, NN);
  scatter_kernel<<<(NE + 255) / 256, 256, 0, stream>>>(row, col, dinv, cursor, csr, NE);

  {
    dim3 grid(HID_C / 128, (NN + 127) / 128);
    gemm_mfma<true><<<grid, 256, 0, stream>>>(x, W1t, Hb, NN, HID_C);
  }
  agg256_bf<<<(NN + 7) / 8, 256, 0, stream>>>(Hb, row_off, csr, dinv, b1, H2b, NN);

  {
    dim3 grid(OUT_C / 128, (NN + 127) / 128);
    gemm_mfma<false><<<grid, 256, 0, stream>>>(H2b, W2t, H3b, NN, OUT_C);
  }
  agg128_bf<<<(NN + 15) / 16, 256, 0, stream>>>(H3b, row_off, csr, dinv, b2, out, NN);
}